// Round 1
// baseline (634.237 us; speedup 1.0000x reference)
//
#include <hip/hip_runtime.h>
#include <math.h>

// feat_1: (16,32,256,256) f32; feat_2: (16,32,64,64) f32; xcorr/out: (16,32,319,319) f32
#define H1 256
#define W1 256
#define HO 319
#define WO 319
#define SEG 16           // row segments per channel; one WAVE per (channel, segment)
#define ROWS_PER 20      // ceil(319/16)

__device__ __forceinline__ float up0(float x, int d, int lane) {
  float s = __shfl_up(x, (unsigned)d, 64);
  return (lane >= d) ? s : 0.0f;
}
__device__ __forceinline__ float dn0(float x, int d, int lane) {
  float s = __shfl_down(x, (unsigned)d, 64);
  return (lane + d <= 63) ? s : 0.0f;
}

// Given this lane's 4 column values a0..a3 (cols 4*lane .. 4*lane+3, all >= 0),
// produce the 64-wide windowed sums:
//   wi[j]: window ending at xo = 4*lane+j        (interior, clipped at 0)
//   wt[j]: window ending at xo = 256+4*lane+j    (tail, clipped at 255)
// All values are built from ADDITIONS of in-window values only -> no cancellation.
__device__ __forceinline__ void win7(float a0, float a1, float a2, float a3,
                                     int lane, float wi[4], float wt[4]) {
  float L0 = a0, L1 = L0 + a1, L2 = L1 + a2, L3 = L2 + a3;  // in-thread prefixes
  float sf2 = a3, sf1 = sf2 + a2, sf0 = sf1 + a1;           // in-thread suffixes (slots > j)
  // backward windowed sums of thread totals (pow2 doubling)
  float b1 = L3 + up0(L3, 1, lane);   // 2-window incl
  float b2 = b1 + up0(b1, 2, lane);   // 4-window incl
  float b3 = b2 + up0(b2, 4, lane);   // 8-window incl
  // M = sum of totals over lanes [lane-15, lane-1] (clipped at 0): 8+4+2+1 decomposition
  float M = up0(b3, 1, lane) + up0(b2, 9, lane) + up0(b1, 13, lane) + up0(L3, 15, lane);
  // forward 16-window inclusive of totals (for right-clipped tail windows)
  float c1 = L3 + dn0(L3, 1, lane);
  float c2 = c1 + dn0(c1, 2, lane);
  float c3 = c2 + dn0(c2, 4, lane);
  float c4 = c3 + dn0(c3, 8, lane);
  float T49 = dn0(c4, 49, lane);      // sum of totals over lanes [lane+49, 63]
  // partial-thread pieces from lane-16 (interior) and lane+48 (tail)
  float g0 = up0(sf0, 16, lane), g1 = up0(sf1, 16, lane), g2 = up0(sf2, 16, lane);
  float h0 = dn0(sf0, 48, lane), h1 = dn0(sf1, 48, lane), h2 = dn0(sf2, 48, lane);
  wi[0] = g0 + M + L0;  wi[1] = g1 + M + L1;  wi[2] = g2 + M + L2;  wi[3] = M + L3;
  wt[0] = h0 + T49;     wt[1] = h1 + T49;     wt[2] = h2 + T49;     wt[3] = T49;
}

__device__ __forceinline__ float out_val(float ws, float ws2, float xc,
                                         float mean, float ssd) {
  const float FLOOR_  = 1.1920928955078125e-07f;  // float32 eps
  const float FLOOR2_ = FLOOR_ * FLOOR_;
  float num  = xc - ws * mean;
  float w2c  = ws2 - ws * ws * (1.0f / 4096.0f);
  float t    = fmaxf(w2c * ssd, 0.0f);            // denom^2
  float numc = fmaxf(num, FLOOR_);                // (num << FLT_MAX always; skip upper clip)
  return (t > FLOOR2_) ? (numc * __frsqrt_rn(t)) : 0.0f;
}

__global__ __launch_bounds__(256, 8)
void ncc_norm_kernel(const float* __restrict__ feat1,
                     const float* __restrict__ feat2,
                     const float* __restrict__ xcorr,
                     float* __restrict__ out) {
  const int tid  = threadIdx.x;
  const int lane = tid & 63;
  const int wv   = tid >> 6;

  // XCD-chunked swizzle (grid = 2048 = 8 XCD * 256, bijective):
  // block d lands on XCD d&7; give that XCD a contiguous chunk of 64 channels,
  // with a channel's 4 blocks adjacent in dispatch order on the same XCD.
  const int d   = blockIdx.x;          // 0..2047
  const int xcd = d & 7;
  const int i   = d >> 3;              // 0..255
  const int bc  = xcd * 64 + (i >> 2); // 0..511 channel
  const int seg = (i & 3) * 4 + wv;    // 0..15 row segment

  const float* f1 = feat1 + (size_t)bc * (H1 * W1);
  const float* f2 = feat2 + (size_t)bc * 4096;

  // ---- per-wave feat_2 stats (no cross-wave sync needed) ----
  float sum = 0.0f, sumsq = 0.0f;
  #pragma unroll
  for (int r = 0; r < 16; ++r) {
    float4 q = *(const float4*)(f2 + r * 256 + 4 * lane);
    sum   += (q.x + q.y) + (q.z + q.w);
    sumsq += (q.x * q.x + q.y * q.y) + (q.z * q.z + q.w * q.w);
  }
  #pragma unroll
  for (int dd = 1; dd < 64; dd <<= 1) {
    sum   += __shfl_xor(sum,   dd, 64);
    sumsq += __shfl_xor(sumsq, dd, 64);
  }
  float mean = sum * (1.0f / 4096.0f);
  float ssd  = sumsq - sum * mean;   // sum((x-mean)^2); terms ~4096 vs ~1, no cancellation

  const int y0 = seg * ROWS_PER;
  const int y1 = min(HO, y0 + ROWS_PER);
  const int x4 = 4 * lane;

  // ---- vertical running window sums (fp64 registers; exact to ~1e-12) ----
  double v0 = 0, v1 = 0, v2 = 0, v3 = 0;      // sum of f1 over vertical window, per slot
  double q0 = 0, q1 = 0, q2 = 0, q3 = 0;      // sum of f1^2
  for (int r = max(0, y0 - 64); r < min(y0, H1); ++r) {
    float4 t = *(const float4*)(f1 + r * W1 + x4);
    v0 += t.x; q0 += (double)t.x * t.x;
    v1 += t.y; q1 += (double)t.y * t.y;
    v2 += t.z; q2 += (double)t.z * t.z;
    v3 += t.w; q3 += (double)t.w * t.w;
  }

  // ---- software prefetch of entering/leaving feat_1 rows ----
  float4 tE, tL;
  if (y0 < H1)  tE = *(const float4*)(f1 + y0 * W1 + x4);
  if (y0 >= 64) tL = *(const float4*)(f1 + (y0 - 64) * W1 + x4);

  for (int y = y0; y < y1; ++y) {
    const int rowbase = (bc * HO + y) * WO;
    const float* xr  = xcorr + rowbase;
    float*       orw = out   + rowbase;

    // issue this row's streaming xcorr loads first (non-temporal: zero reuse)
    float xi[4];
    #pragma unroll
    for (int j = 0; j < 4; ++j) xi[j] = __builtin_nontemporal_load(xr + x4 + j);
    float xt[4] = {0.0f, 0.0f, 0.0f, 0.0f};
    if (lane < 16) {
      xt[0] = __builtin_nontemporal_load(xr + 256 + x4 + 0);
      xt[1] = __builtin_nontemporal_load(xr + 256 + x4 + 1);
      xt[2] = __builtin_nontemporal_load(xr + 256 + x4 + 2);
      if (lane < 15) xt[3] = __builtin_nontemporal_load(xr + 256 + x4 + 3);
    }

    // consume prefetched rows (uniform branches)
    if (y < H1) {
      v0 += tE.x; q0 += (double)tE.x * tE.x;
      v1 += tE.y; q1 += (double)tE.y * tE.y;
      v2 += tE.z; q2 += (double)tE.z * tE.z;
      v3 += tE.w; q3 += (double)tE.w * tE.w;
    }
    if (y >= 64) {
      v0 -= tL.x; q0 -= (double)tL.x * tL.x;
      v1 -= tL.y; q1 -= (double)tL.y * tL.y;
      v2 -= tL.z; q2 -= (double)tL.z * tL.z;
      v3 -= tL.w; q3 -= (double)tL.w * tL.w;
    }

    // prefetch rows for iteration y+1 (hide L2/HBM latency under win7 chain)
    {
      int yn = y + 1;
      if (yn < y1) {
        if (yn < H1)  tE = *(const float4*)(f1 + yn * W1 + x4);
        if (yn >= 64) tL = *(const float4*)(f1 + (yn - 64) * W1 + x4);
      }
    }

    // fp32 per-column vertical sums for this output row
    float w0 = (float)v0, w1 = (float)v1, w2 = (float)v2, w3 = (float)v3;
    float u0 = (float)q0, u1 = (float)q1, u2 = (float)q2, u3 = (float)q3;

    float wsI[4], wsT[4], sqI[4], sqT[4];
    win7(w0, w1, w2, w3, lane, wsI, wsT);
    win7(u0, u1, u2, u3, lane, sqI, sqT);

    // interior outputs xo = 4*lane + j (rows are 319 floats -> 4B aligned: scalar I/O)
    #pragma unroll
    for (int j = 0; j < 4; ++j)
      __builtin_nontemporal_store(out_val(wsI[j], sqI[j], xi[j], mean, ssd),
                                  orw + x4 + j);
    // tail outputs xo = 256 + 4*lane + j (lanes 0..15 only; 63 elements)
    if (lane < 16) {
      __builtin_nontemporal_store(out_val(wsT[0], sqT[0], xt[0], mean, ssd), orw + 256 + x4 + 0);
      __builtin_nontemporal_store(out_val(wsT[1], sqT[1], xt[1], mean, ssd), orw + 256 + x4 + 1);
      __builtin_nontemporal_store(out_val(wsT[2], sqT[2], xt[2], mean, ssd), orw + 256 + x4 + 2);
      if (lane < 15)
        __builtin_nontemporal_store(out_val(wsT[3], sqT[3], xt[3], mean, ssd), orw + 256 + x4 + 3);
    }
  }
}

extern "C" void kernel_launch(void* const* d_in, const int* in_sizes, int n_in,
                              void* d_out, int out_size, void* d_ws, size_t ws_size,
                              hipStream_t stream) {
  const float* feat1 = (const float*)d_in[0];
  const float* feat2 = (const float*)d_in[1];
  const float* xcorr = (const float*)d_in[2];
  float* out = (float*)d_out;

  dim3 grid(512 * SEG / 4);   // 2048 blocks, 4 waves/block, one wave per (channel, segment)
  ncc_norm_kernel<<<grid, 256, 0, stream>>>(feat1, feat2, xcorr, out);
}